// Round 6
// baseline (268.458 us; speedup 1.0000x reference)
//
#include <hip/hip_runtime.h>

// LSTM: B=4096, T=1024, I=8, H=4. fp32.
// R6 = R4 structure (best measured) + short-latency chain activations.
//  - wave 0 (producer): global_load_lds x staging (contiguous 1KB/instr) +
//    input projection -> double-buffered LDS pre-act ring. Rows pre-scaled:
//    i,o by -log2e (exp2-domain sigmoid), g by 2log2e, f by 0.5 (Pade path).
//  - wave 1 (consumer): serial scan, per-step float4 pre-act read (R4
//    pattern; R5's register batching regressed). Chain-critical activations
//    sigmoid(f) and tanh(c) use an fma+rcp Pade[5/6] (err <= 1.1e-3):
//    kills 2 serial v_exp latencies/step. Off-chain i,g,o stay exact
//    (their latency overlaps the f-path).
// Evidence: R3->R4 (-50cyc issue: no change) and R4->R5 (LDS batching:
// regression) => consumer is latency-bound on the f->c->tanh(c) chain.

#define TT 1024
#define II 8
#define CHUNK 32
#define NCHUNK (TT / CHUNK)  // 32
#define ROW (CHUNK * II)     // 256 floats x per stream per chunk
#define SPAD 4

#define L2E 1.4426950408889634f
#define I_SCALE (-L2E)       // i,o rows: sig via rcp(1+exp2(-log2e*z))
#define F_SCALE 0.5f         // f row: sig via 0.5+0.5*pade_tanh(z/2)
#define G_SCALE (2.0f * L2E) // g row: tanh via 1-2*rcp(1+exp2(2log2e*z))

typedef float v2f __attribute__((ext_vector_type(2)));

template <int CTRL>
__device__ __forceinline__ float dppf(float v) {
  return __int_as_float(
      __builtin_amdgcn_mov_dpp(__float_as_int(v), CTRL, 0xF, 0xF, true));
}

__device__ __forceinline__ float ex2(float x) {
  return __builtin_amdgcn_exp2f(x);
}
__device__ __forceinline__ float rcp(float x) {
  return __builtin_amdgcn_rcpf(x);
}

// tanh via Pade[5/6] (continued-fraction): x(945+105x^2+x^4)/(945+420x^2+15x^4)
// on clamp(x,+-4.5), result clamped to +-1. Max err ~1.1e-3 (at |x|~3.6-3.8);
// exact through x^11 near 0; beyond 4.5 returns 1 (true tanh >= 0.99975).
__device__ __forceinline__ float pade_tanh(float x) {
  const float xc = __builtin_amdgcn_fmed3f(x, -4.5f, 4.5f);
  const float x2 = xc * xc;
  const float nin = fmaf(x2, x2 + 105.0f, 945.0f);
  const float den = fmaf(x2, fmaf(15.0f, x2, 420.0f), 945.0f);
  const float t = (xc * nin) * rcp(den);
  return __builtin_amdgcn_fmed3f(t, -1.0f, 1.0f);
}

#define GLOAD_LDS16(gp, lp)                                   \
  __builtin_amdgcn_global_load_lds(                           \
      (const __attribute__((address_space(1))) void*)(gp),    \
      (__attribute__((address_space(3))) void*)(lp), 16, 0, 0)

__global__ __launch_bounds__(128, 1) void lstm_fused(
    const float* __restrict__ x, const float* __restrict__ W_ih,
    const float* __restrict__ W_hh, const float* __restrict__ b_ih,
    const float* __restrict__ b_hh, const float* __restrict__ fc_w,
    const float* __restrict__ fc_b, float* __restrict__ out, int B) {
  const int tid = threadIdx.x;
  const int wave = tid >> 6;
  const int lane = tid & 63;
  const int j = lane & 3;
  const int grp = lane >> 2;
  const int b = blockIdx.x * 16 + grp;

  __shared__ float xs0[16][ROW + SPAD];
  __shared__ float xs1[16][ROW + SPAD];
  // pre-act ring: [step][stream][j*4 + gate]; lane rw one contiguous float4,
  // wave touches 1KB stride-1 per step (2-way bank alias = free).
  __shared__ float pa0[CHUNK][16][16];
  __shared__ float pa1[CHUNK][16][16];

  if (wave == 0) {
    // ---------------- producer ----------------
    v2f wih01[II], wih23[II];
    v2f bias01, bias23;
#pragma unroll
    for (int k = 0; k < II; ++k) {
      wih01[k] = v2f{I_SCALE * W_ih[(0 * 4 + j) * II + k],
                     F_SCALE * W_ih[(1 * 4 + j) * II + k]};
      wih23[k] = v2f{G_SCALE * W_ih[(2 * 4 + j) * II + k],
                     I_SCALE * W_ih[(3 * 4 + j) * II + k]};
    }
    bias01 = v2f{I_SCALE * (b_ih[0 * 4 + j] + b_hh[0 * 4 + j]),
                 F_SCALE * (b_ih[1 * 4 + j] + b_hh[1 * 4 + j])};
    bias23 = v2f{G_SCALE * (b_ih[2 * 4 + j] + b_hh[2 * 4 + j]),
                 I_SCALE * (b_ih[3 * 4 + j] + b_hh[3 * 4 + j])};

    const size_t blockBase = (size_t)blockIdx.x * 16;

    auto issue = [&](float(*xs)[ROW + SPAD], int t0) {
#pragma unroll
      for (int s = 0; s < 16; ++s) {
        const float* gp =
            x + (blockBase + s) * (TT * II) + (size_t)t0 * II + lane * 4;
        GLOAD_LDS16(gp, &xs[s][0]);
      }
    };

    auto produce = [&](float(*pa)[16][16], const float(*xs)[ROW + SPAD]) {
      const float* row = &xs[grp][0];
#pragma unroll 8
      for (int u = 0; u < CHUNK; ++u) {
        const float4 xa = *(const float4*)(row + u * 8);
        const float4 xb = *(const float4*)(row + u * 8 + 4);
        v2f a01 = bias01, a23 = bias23;
#define XFMA(k, val)                                    \
  {                                                     \
    v2f xv = v2f{(val), (val)};                         \
    a01 = __builtin_elementwise_fma(wih01[k], xv, a01); \
    a23 = __builtin_elementwise_fma(wih23[k], xv, a23); \
  }
        XFMA(0, xa.x) XFMA(1, xa.y) XFMA(2, xa.z) XFMA(3, xa.w)
        XFMA(4, xb.x) XFMA(5, xb.y) XFMA(6, xb.z) XFMA(7, xb.w)
#undef XFMA
        *(float4*)&pa[u][grp][j * 4] = float4{a01.x, a01.y, a23.x, a23.y};
      }
    };

    issue(xs0, 0);
    issue(xs1, CHUNK);
    produce(pa0, xs0);
    __syncthreads();

    for (int ck = 0; ck < NCHUNK; ++ck) {
      if (ck + 1 < NCHUNK)
        produce(((ck + 1) & 1) ? pa1 : pa0, ((ck + 1) & 1) ? xs1 : xs0);
      if (ck + 2 < NCHUNK) issue((ck & 1) ? xs1 : xs0, (ck + 2) * CHUNK);
      __syncthreads();
    }
  } else {
    // ---------------- consumer (serial scan) ----------------
    v2f whh01[4], whh23[4];
#pragma unroll
    for (int k = 0; k < 4; ++k) {
      whh01[k] = v2f{I_SCALE * W_hh[(0 * 4 + j) * 4 + k],
                     F_SCALE * W_hh[(1 * 4 + j) * 4 + k]};
      whh23[k] = v2f{G_SCALE * W_hh[(2 * 4 + j) * 4 + k],
                     I_SCALE * W_hh[(3 * 4 + j) * 4 + k]};
    }
    float h = 0.0f, c = 0.0f;  // c carried PLAIN (Pade tanh input)

    auto step = [&](float4 g) {
      const float h0 = dppf<0x00>(h);
      const float h1 = dppf<0x55>(h);
      const float h2 = dppf<0xAA>(h);
      const float h3 = dppf<0xFF>(h);
      v2f a01 = v2f{g.x, g.y};
      v2f a23 = v2f{g.z, g.w};
#define HFMA(k, val)                                    \
  {                                                     \
    v2f hv = v2f{(val), (val)};                         \
    a01 = __builtin_elementwise_fma(whh01[k], hv, a01); \
    a23 = __builtin_elementwise_fma(whh23[k], hv, a23); \
  }
      HFMA(0, h0) HFMA(1, h1) HFMA(2, h2) HFMA(3, h3)
#undef HFMA
      // off-chain (latency overlaps the f-path): exact exp2-domain
      const float ig = rcp(1.0f + ex2(a01.x));          // sig(i)
      const float og = rcp(1.0f + ex2(a23.y));          // sig(o)
      const float rg = rcp(1.0f + ex2(a23.x));          // (1-tanh g)/2
      const float gg = fmaf(rg, -2.0f, 1.0f);           // tanh(g)
      // chain-critical: Pade, no exp latency
      const float fg = fmaf(pade_tanh(a01.y), 0.5f, 0.5f);  // sig(f)
      c = fmaf(fg, c, ig * gg);
      h = og * pade_tanh(c);
    };

    __syncthreads();

    for (int ck = 0; ck < NCHUNK; ++ck) {
      const float(*pa)[16][16] = (ck & 1) ? pa1 : pa0;
      const float* base = &pa[0][grp][j * 4];
      float4 g = *(const float4*)base;
#pragma unroll 8
      for (int u = 0; u < CHUNK; ++u) {
        const int un = (u + 1 < CHUNK) ? (u + 1) : u;  // clamp tail
        const float4 gn = *(const float4*)(base + un * 256);
        step(g);
        g = gn;
      }
      __syncthreads();
    }

    // final FC: out[b] = sum_j h_j * fc_w[j] + fc_b
    float v = h * fc_w[j];
    v += dppf<0xB1>(v);  // quad_perm [1,0,3,2]
    v += dppf<0x4E>(v);  // quad_perm [2,3,0,1]
    if (j == 0 && b < B) out[b] = v + fc_b[0];
  }
}

extern "C" void kernel_launch(void* const* d_in, const int* in_sizes, int n_in,
                              void* d_out, int out_size, void* d_ws,
                              size_t ws_size, hipStream_t stream) {
  const float* x = (const float*)d_in[0];
  const float* W_ih = (const float*)d_in[1];
  const float* W_hh = (const float*)d_in[2];
  const float* b_ih = (const float*)d_in[3];
  const float* b_hh = (const float*)d_in[4];
  const float* fc_w = (const float*)d_in[5];
  const float* fc_b = (const float*)d_in[6];
  float* out = (float*)d_out;

  const int B = in_sizes[0] / (TT * II);
  const int nblocks = (B + 15) / 16;
  lstm_fused<<<nblocks, 128, 0, stream>>>(x, W_ih, W_hh, b_ih, b_hh, fc_w,
                                          fc_b, out, B);
}